// Round 9
// baseline (1046.656 us; speedup 1.0000x reference)
//
#include <hip/hip_runtime.h>
#include <stdint.h>

// ---------- helpers ----------
typedef __attribute__((ext_vector_type(8))) short bf16x8;
typedef __attribute__((ext_vector_type(4))) float f32x4;

__device__ __forceinline__ unsigned short f2bf(float f) {
  union { float f; unsigned u; } v; v.f = f;
  unsigned r = v.u + 0x7fffu + ((v.u >> 16) & 1u);   // RNE
  return (unsigned short)(r >> 16);
}
__device__ __forceinline__ float bf2f(unsigned short u) {
  union { unsigned u; float f; } v; v.u = ((unsigned)u) << 16; return v.f;
}
__device__ __forceinline__ void gload16(const void* g, void* l) {
  __builtin_amdgcn_global_load_lds(
      (const __attribute__((address_space(1))) unsigned int*)(uintptr_t)g,
      (__attribute__((address_space(3))) unsigned int*)(uintptr_t)l,
      16, 0, 0);
}

// ---------- kernel 1: gate + LN, one wave per row, no barriers ----------
__global__ __launch_bounds__(256)
void k_gate_ln(const float* __restrict__ x, const int* __restrict__ dmask,
               const float* __restrict__ gw1, const float* __restrict__ gb1,
               const float* __restrict__ gw2, const float* __restrict__ gb2,
               const float* __restrict__ sb, const float* __restrict__ bb,
               const float* __restrict__ si, const float* __restrict__ bi,
               float* __restrict__ wout,          // [rows][4] f32: w0,w1,w2,0
               unsigned short* __restrict__ z)    // [2*rows][1024] bf16 interleaved
{
  const int lane = threadIdx.x & 63;
  const int row = blockIdx.x * 4 + (threadIdx.x >> 6);
  const float* xr = x + (size_t)row * 1024;

  float4 xv[4];
  float p0 = 0.f, p1 = 0.f, p2 = 0.f, p3 = 0.f, s = 0.f, ss = 0.f;
#pragma unroll
  for (int j = 0; j < 4; ++j) {
    const int i0 = lane * 4 + j * 256;
    xv[j] = *(const float4*)(xr + i0);
    const float xc[4] = {xv[j].x, xv[j].y, xv[j].z, xv[j].w};
#pragma unroll
    for (int c = 0; c < 4; ++c) {
      const float4 w = *(const float4*)(gw1 + (size_t)(i0 + c) * 4);
      p0 += xc[c] * w.x; p1 += xc[c] * w.y; p2 += xc[c] * w.z; p3 += xc[c] * w.w;
      s += xc[c]; ss += xc[c] * xc[c];
    }
  }
#pragma unroll
  for (int m = 32; m >= 1; m >>= 1) {
    p0 += __shfl_xor(p0, m, 64); p1 += __shfl_xor(p1, m, 64);
    p2 += __shfl_xor(p2, m, 64); p3 += __shfl_xor(p3, m, 64);
    s  += __shfl_xor(s,  m, 64); ss += __shfl_xor(ss, m, 64);
  }
  const float h0 = fmaxf(p0 + gb1[0], 0.f), h1 = fmaxf(p1 + gb1[1], 0.f);
  const float h2 = fmaxf(p2 + gb1[2], 0.f), h3 = fmaxf(p3 + gb1[3], 0.f);
  float lg[4];
#pragma unroll
  for (int e = 0; e < 4; ++e) {
    float val = h0 * gw2[e] + h1 * gw2[4 + e] + h2 * gw2[8 + e] + h3 * gw2[12 + e] + gb2[e];
    lg[e] = (dmask[e] == 0) ? -1.0e9f : val;
  }
  const float mx = fmaxf(fmaxf(lg[0], lg[1]), fmaxf(lg[2], lg[3]));
  const float e0 = expf(lg[0] - mx), e1 = expf(lg[1] - mx);
  const float e2 = expf(lg[2] - mx), e3 = expf(lg[3] - mx);
  const float inv = 1.f / (e0 + e1 + e2 + e3);
  if (lane == 0) {
    float4 wv; wv.x = e0 * inv; wv.y = e1 * inv; wv.z = e2 * inv; wv.w = 0.f;
    *(float4*)(wout + (size_t)row * 4) = wv;
  }
  const float mean = s * (1.f / 1024.f);
  const float rstd = rsqrtf(ss * (1.f / 1024.f) - mean * mean + 1e-6f);

#pragma unroll
  for (int j = 0; j < 4; ++j) {
    const int i0 = lane * 4 + j * 256;
    const float4 sbv = *(const float4*)(sb + i0);
    const float4 bbv = *(const float4*)(bb + i0);
    const float4 siv = *(const float4*)(si + i0);
    const float4 biv = *(const float4*)(bi + i0);
    const float xc[4] = {xv[j].x, xv[j].y, xv[j].z, xv[j].w};
    const float sbs[4] = {sbv.x, sbv.y, sbv.z, sbv.w};
    const float bbs[4] = {bbv.x, bbv.y, bbv.z, bbv.w};
    const float sis[4] = {siv.x, siv.y, siv.z, siv.w};
    const float bis[4] = {biv.x, biv.y, biv.z, biv.w};
    ushort4 zb, zi;
    unsigned short zbv[4], ziv[4];
#pragma unroll
    for (int c = 0; c < 4; ++c) {
      const float xn = (xc[c] - mean) * rstd;
      zbv[c] = f2bf(xn * sbs[c] + bbs[c]);
      ziv[c] = f2bf(xn * sis[c] + bis[c]);
    }
    zb.x = zbv[0]; zb.y = zbv[1]; zb.z = zbv[2]; zb.w = zbv[3];
    zi.x = ziv[0]; zi.y = ziv[1]; zi.z = ziv[2]; zi.w = ziv[3];
    *(ushort4*)(z + (size_t)(2 * row) * 1024 + i0) = zb;
    *(ushort4*)(z + (size_t)(2 * row + 1) * 1024 + i0) = zi;
  }
}

// ---------- kernel 2: both weight transposes in one launch ----------
__global__ __launch_bounds__(256)
void k_transpose2(const float* __restrict__ s1, unsigned short* __restrict__ d1,
                  const float* __restrict__ s2, unsigned short* __restrict__ d2)
{
  __shared__ float tile[32][33];
  int bid = blockIdx.x;
  const float* src; unsigned short* dst; int R, C, bx, by;
  if (bid < 2048) { src = s1; dst = d1; R = 1024; C = 2048; bx = bid & 63; by = bid >> 6; }
  else { bid -= 2048; src = s2; dst = d2; R = 2048; C = 1024; bx = bid & 31; by = bid >> 5; }
  const int tx = threadIdx.x & 31, ty = threadIdx.x >> 5;
  const int c0 = bx * 32, r0 = by * 32;
#pragma unroll
  for (int j = 0; j < 32; j += 8)
    tile[ty + j][tx] = src[(size_t)(r0 + ty + j) * C + c0 + tx];
  __syncthreads();
#pragma unroll
  for (int j = 0; j < 32; j += 8)
    dst[(size_t)(c0 + ty + j) * R + r0 + tx] = f2bf(tile[tx][ty + j]);
}

// ---------- kernel 3: 256x256 bf16 GEMM, SINGLE 64KB buffer -> 2 blocks/CU ----------
// 8 waves (2Mx4N, 128x64/wave), acc[8][4]=128 VGPR, launch_bounds(512,4) pins <=128.
// Overlap mechanism: co-resident blocks de-synchronized (no shared barriers) -> one
// block's MFMA covers the other's ds_read/stage (m114). Epilogues in two 64KB halves.
#define LOADA(dst, q) do {                                                            \
  dst[0][0] = *(const bf16x8*)(curA + (arowB + (2*(q)+0)*16) * 128 + koff0);          \
  dst[0][1] = *(const bf16x8*)(curA + (arowB + (2*(q)+0)*16) * 128 + koff1);          \
  dst[1][0] = *(const bf16x8*)(curA + (arowB + (2*(q)+1)*16) * 128 + koff0);          \
  dst[1][1] = *(const bf16x8*)(curA + (arowB + (2*(q)+1)*16) * 128 + koff1);          \
} while (0)

#define MFMAQ(src, q) do {                                                            \
  __builtin_amdgcn_s_setprio(1);                                                      \
  _Pragma("unroll")                                                                   \
  for (int i = 0; i < 2; ++i) {                                                       \
    _Pragma("unroll")                                                                 \
    for (int ni = 0; ni < 4; ++ni) {                                                  \
      acc[2*(q)+i][ni] = __builtin_amdgcn_mfma_f32_16x16x32_bf16(src[i][0], bf[ni][0], acc[2*(q)+i][ni], 0, 0, 0); \
      acc[2*(q)+i][ni] = __builtin_amdgcn_mfma_f32_16x16x32_bf16(src[i][1], bf[ni][1], acc[2*(q)+i][ni], 0, 0, 0); \
    } }                                                                               \
  __builtin_amdgcn_s_setprio(0);                                                      \
} while (0)

template <int MODE, int K, int NBX>
__global__ __launch_bounds__(512, 4)
void gemm256(const unsigned short* __restrict__ A,
             const unsigned short* __restrict__ Bt,
             const float* __restrict__ bias,
             unsigned short* __restrict__ Cb,
             const float* __restrict__ x,
             const float* __restrict__ wgt,
             float* __restrict__ outp)
{
  constexpr int NKT = K / 64;
  constexpr int N = NBX * 256;
  __shared__ __align__(16) char lds[65536];   // A[256][64] @0 (32KB), B[256][64] @32768

  const int tid = threadIdx.x;
  const int wave = tid >> 6, lane = tid & 63;
  const int lr = lane & 15, lk = lane >> 4;
  const int wm = wave >> 2, wn = wave & 3;

  // XCD-aware bijective block swizzle (gridDim.x % 8 == 0)
  const int cpx = (int)gridDim.x >> 3;
  const int flat = (int)blockIdx.x;
  const int swz = (flat & 7) * cpx + (flat >> 3);
  const int bm0 = (swz / NBX) * 256;
  const int bn0 = (swz % NBX) * 256;

  // staging: inverse-swizzled global source, linear LDS dest (rule #21, verified)
  const int srow = tid >> 3;
  const int schunk = ((tid & 7) ^ (srow & 7)) * 8;
  const unsigned short* aSrc = A + (size_t)(bm0 + srow) * K + schunk;
  const unsigned short* bSrc = Bt + (size_t)(bn0 + srow) * K + schunk;
  const int ldsWaveOff = wave * 1024;

  // read-side swizzled k-offsets (verified: 0 bank conflicts)
  const int xorv = (lr & 7) << 4;
  const int koff0 = (lk * 16) ^ xorv;
  const int koff1 = (64 + lk * 16) ^ xorv;
  const int arowB = wm * 128 + lr;
  const int browB = wn * 64 + lr;

  f32x4 acc[8][4] = {};

  auto stage_tile = [&](int tt) {
#pragma unroll
    for (int h = 0; h < 4; ++h) {   // {B-lo, B-hi, A-lo, A-hi}
      const unsigned short* sp = (h < 2 ? bSrc : aSrc) + (size_t)((h & 1) * 128) * K + tt * 64;
      char* d = lds + ((h < 2) ? 32768 : 0) + ((h & 1) << 14) + ldsWaveOff;
      gload16(sp, d);
      gload16(sp + (size_t)64 * K, d + 8192);
    }
  };

  stage_tile(0);
  asm volatile("s_waitcnt vmcnt(0)" ::: "memory");
  __builtin_amdgcn_s_barrier();

  for (int t = 0; t < NKT; ++t) {
    const char* curA = lds;
    const char* curB = lds + 32768;

    bf16x8 bf[4][2];
#pragma unroll
    for (int ni = 0; ni < 4; ++ni) {
      bf[ni][0] = *(const bf16x8*)(curB + (browB + ni * 16) * 128 + koff0);
      bf[ni][1] = *(const bf16x8*)(curB + (browB + ni * 16) * 128 + koff1);
    }
    bf16x8 a0[2][2], a1[2][2];
    LOADA(a0, 0);
    LOADA(a1, 1);
    MFMAQ(a0, 0);  LOADA(a0, 2);
    MFMAQ(a1, 1);  LOADA(a1, 3);
    MFMAQ(a0, 2);
    MFMAQ(a1, 3);

    if (t + 1 < NKT) {
      __builtin_amdgcn_s_barrier();            // all reads of this tile done
      stage_tile(t + 1);                       // overwrite same buffer
      asm volatile("s_waitcnt vmcnt(0)" ::: "memory");
      __builtin_amdgcn_s_barrier();            // staged data visible to all
    }
  }

  __syncthreads();   // LDS reuse for epilogue retile

  if (MODE == 0) {
    // bf16 tile in two 64KB halves: [256 rows][256B], swizzle byte ^= (row&7)<<4
#pragma unroll
    for (int h = 0; h < 2; ++h) {
      if ((wn >> 1) == h) {                    // wave-uniform writer set
#pragma unroll
        for (int ni = 0; ni < 4; ++ni) {
          const int col = wn * 64 + ni * 16 + lr;
          const int lcolb = (col & 127) * 2;
          const float bv = bias[bn0 + col];
#pragma unroll
          for (int mi = 0; mi < 8; ++mi) {
#pragma unroll
            for (int j = 0; j < 4; ++j) {
              const int row = wm * 128 + mi * 16 + lk * 4 + j;
              float v = fmaxf(acc[mi][ni][j] + bv, 0.f);
              *(unsigned short*)(lds + row * 256 + (lcolb ^ ((row & 7) << 4))) = f2bf(v);
            }
          }
        }
      }
      __syncthreads();
#pragma unroll
      for (int sx = 0; sx < 8; ++sx) {
        const int row = wave * 32 + sx * 4 + (lane >> 4);
        const int chunk = lane & 15;
        bf16x8 vv = *(const bf16x8*)(lds + row * 256 + ((chunk * 16) ^ ((row & 7) << 4)));
        *(bf16x8*)(Cb + (size_t)(bm0 + row) * N + bn0 + h * 128 + chunk * 8) = vv;
      }
      if (h == 0) __syncthreads();
    }
  } else {
    // mix epilogue in two 64KB halves: [64 orows][1024B], swizzle ^= (orow&6)<<5
    const int orbase = bm0 >> 1;
#pragma unroll
    for (int h = 0; h < 2; ++h) {
      if (wm == h) {                           // wave-uniform writer set
#pragma unroll
        for (int mi = 0; mi < 8; ++mi) {
          const int lr0 = mi * 8 + lk * 2;     // local orow in [0,64)
          const int gr0 = orbase + h * 64 + lr0;
          const float4 wa = *(const float4*)(wgt + (size_t)gr0 * 4);
          const float4 wb = *(const float4*)(wgt + (size_t)(gr0 + 1) * 4);
#pragma unroll
          for (int ni = 0; ni < 4; ++ni) {
            const int colb = (wn * 64 + ni * 16 + lr) * 4;
            const float bv = bias[bn0 + wn * 64 + ni * 16 + lr];
            float m0 = wa.y * (acc[mi][ni][0] + bv) + wa.z * (acc[mi][ni][1] + bv);
            float m1 = wb.y * (acc[mi][ni][2] + bv) + wb.z * (acc[mi][ni][3] + bv);
            *(float*)(lds + (size_t)lr0 * 1024 + (colb ^ ((lr0 & 6) << 5))) = m0;
            *(float*)(lds + (size_t)(lr0 + 1) * 1024 + (colb ^ (((lr0 + 1) & 6) << 5))) = m1;
          }
        }
      }
      __syncthreads();
#pragma unroll
      for (int sx = 0; sx < 8; ++sx) {
        const int lrow = wave * 8 + sx;
        const int gor = orbase + h * 64 + lrow;
        f32x4 m = *(const f32x4*)(lds + (size_t)lrow * 1024 + ((lane * 16) ^ ((lrow & 6) << 5)));
        const float4 xv = *(const float4*)(x + (size_t)gor * 1024 + bn0 + lane * 4);
        const float w0 = wgt[(size_t)gor * 4];
        f32x4 o;
        o[0] = xv.x * (1.f + w0) + m[0];
        o[1] = xv.y * (1.f + w0) + m[1];
        o[2] = xv.z * (1.f + w0) + m[2];
        o[3] = xv.w * (1.f + w0) + m[3];
        *(f32x4*)(outp + (size_t)gor * 1024 + bn0 + lane * 4) = o;
      }
      if (h == 0) __syncthreads();
    }
  }
}

// ---------- launch ----------
extern "C" void kernel_launch(void* const* d_in, const int* in_sizes, int n_in,
                              void* d_out, int out_size, void* d_ws, size_t ws_size,
                              hipStream_t stream) {
  const float* x    = (const float*)d_in[0];
  const int*   dm   = (const int*)  d_in[1];
  const float* gw1  = (const float*)d_in[2];
  const float* gb1  = (const float*)d_in[3];
  const float* gw2  = (const float*)d_in[4];
  const float* gb2  = (const float*)d_in[5];
  const float* lsb  = (const float*)d_in[6];
  const float* lbb  = (const float*)d_in[7];
  const float* lsi  = (const float*)d_in[8];
  const float* lbi  = (const float*)d_in[9];
  const float* aw1  = (const float*)d_in[10];
  const float* ab1  = (const float*)d_in[11];
  const float* aw2  = (const float*)d_in[12];
  const float* ab2  = (const float*)d_in[13];
  float* out = (float*)d_out;

  char* ws = (char*)d_ws;
  float*          wgt  = (float*)(ws + 0);                                     // 128KB
  unsigned short* z    = (unsigned short*)(ws + 131072);                       // 32MB (interleaved)
  unsigned short* w1t  = (unsigned short*)(ws + 131072 + 33554432);            // 4MB
  unsigned short* w2t  = (unsigned short*)(ws + 131072 + 33554432 + 4194304);  // 4MB
  unsigned short* hbuf = (unsigned short*)(ws + 131072 + 33554432 + 8388608);  // 64MB

  k_gate_ln<<<2048, 256, 0, stream>>>(x, dm, gw1, gb1, gw2, gb2,
                                      lsb, lbb, lsi, lbi, wgt, z);
  k_transpose2<<<4096, 256, 0, stream>>>(aw1, w1t, aw2, w2t);
  // GEMM1: h = relu(z @ w1 + b1)   [16384 x 2048], K=1024, grid 512 = 2 blocks/CU
  gemm256<0, 1024, 8><<<512, 512, 0, stream>>>(z, w1t, ab1, hbuf, nullptr, nullptr, nullptr);
  // GEMM2 (+fused mix): out = x*(1+w0) + w1*ab + w2*ai   [rows 8192 x 1024], K=2048
  gemm256<1, 2048, 4><<<256, 512, 0, stream>>>(hbuf, w2t, ab2, nullptr, x, wgt, out);
}